// Round 11
// baseline (65.822 us; speedup 1.0000x reference)
//
#include <hip/hip_runtime.h>

typedef _Float16 half8 __attribute__((ext_vector_type(8)));
typedef _Float16 half4 __attribute__((ext_vector_type(4)));
typedef float f32x4 __attribute__((ext_vector_type(4)));
typedef float f32x16 __attribute__((ext_vector_type(16)));

#define S_LEN 2048
#define HDIM 64
#define NT (S_LEN / 64)     // 32 old-format 64-kv tiles
#define NT2 16              // 128-kv super-tiles
#define QRS 258
#define NBH 16
#define L2E 1.44269504f
#define TSTR 72

__device__ __forceinline__ void load_lds16(const void* g, void* l) {
    __builtin_amdgcn_global_load_lds(
        (const __attribute__((address_space(1))) unsigned int*)g,
        (__attribute__((address_space(3))) unsigned int*)l, 16, 0, 0);
}

// ---- fused pre-pass ----------------------------------------------------------------
// blocks 0..1023: K -> per-64kv-tile swizzled fp16 image (unchanged, byte-identical):
//   (bh,t,kv,d) at byte (bh*32+t)*8192 + ((kv*128 + d*2) ^ ((kv&7)<<4))
// blocks 1024..1535: V -> sigma-permuted transposed swizzled image for 32x32 PV:
//   per 64-kv tile: [d=0..63][slot s=0..63] f16, byte (d*128 + s*2) ^ ((d&7)<<4)
//   slot s = gq*32 + c*16 + h*8 + j  ->  kv = 32*gq + 16*c + (j&3) + 8*(j>>2) + 4*h
__global__ __launch_bounds__(256)
void convert_kv_kernel(const float* __restrict__ Kg, const float* __restrict__ Vg,
                       _Float16* __restrict__ Kh, _Float16* __restrict__ Vp)
{
    __shared__ _Float16 tile[64 * TSTR];
    const int bid = blockIdx.x;
    const int tid = threadIdx.x;
    if (bid < 1024) {
        const int id = bid * 256 + tid;
        const int r  = id >> 3;
        const int d0 = (id & 7) * 8;
        const float* src = Kg + (size_t)r * HDIM + d0;
        f32x4 f0 = *(const f32x4*)(src);
        f32x4 f1 = *(const f32x4*)(src + 4);
        half8 h;
#pragma unroll
        for (int j = 0; j < 4; ++j) { h[j] = (_Float16)f0[j]; h[j+4] = (_Float16)f1[j]; }
        const int bh = r >> 11, kvg = r & 2047;
        const int t = kvg >> 6, kv = kvg & 63;
        const size_t blk = (size_t)(bh * NT + t) * 8192;
        const int off = (kv * 128 + d0 * 2) ^ ((kv & 7) << 4);
        *(half8*)((char*)Kh + blk + off) = h;
    } else {
        const int bt = bid - 1024;               // bh*32 + t64
        const int bh = bt >> 5, t = bt & 31;
        {
            const int kv = tid >> 2;
            const int d0 = (tid & 3) * 16;
            const float* src = Vg + ((size_t)bh * S_LEN + t * 64 + kv) * HDIM + d0;
            f32x4 f0 = *(const f32x4*)(src);
            f32x4 f1 = *(const f32x4*)(src + 4);
            f32x4 f2 = *(const f32x4*)(src + 8);
            f32x4 f3 = *(const f32x4*)(src + 12);
            half8 h0, h1;
#pragma unroll
            for (int j = 0; j < 4; ++j) {
                h0[j] = (_Float16)f0[j]; h0[j+4] = (_Float16)f1[j];
                h1[j] = (_Float16)f2[j]; h1[j+4] = (_Float16)f3[j];
            }
            *(half8*)&tile[kv * TSTR + d0]     = h0;
            *(half8*)&tile[kv * TSTR + d0 + 8] = h1;
        }
        __syncthreads();
        {
            const int d = tid >> 2;              // 0..63
            char* base = (char*)Vp + (size_t)bt * 8192;
            const int dsw = (d & 7) << 4;
#pragma unroll
            for (int gi = 0; gi < 2; ++gi) {
                const int g8 = (tid & 3) * 2 + gi;   // 0..7 : slot-group of 8
                const int gq = g8 >> 2, c = (g8 >> 1) & 1, hh = g8 & 1;
                half8 ch;
#pragma unroll
                for (int j = 0; j < 8; ++j) {
                    const int kvloc = 32*gq + 16*c + (j & 3) + 8*(j >> 2) + 4*hh;
                    ch[j] = tile[kvloc * TSTR + d];
                }
                *(half8*)(base + ((d * 128 + g8 * 16) ^ dsw)) = ch;
            }
        }
    }
}

// ---- main attention kernel (v11: 32x32x16 MFMA, KVBLK=128, 1 barrier/supertile) ----
// 8 waves = 2 qh x 4 kq. Wave: S tile 32q x 32kv per supertile; K frags from global.
__global__ __launch_bounds__(512, 4)
void relattn_v11(const float* __restrict__ Qg, const float* __restrict__ RELg,
                 const _Float16* __restrict__ Kh, const _Float16* __restrict__ Vp,
                 float* __restrict__ Og)
{
    __shared__ __attribute__((aligned(16))) _Float16 Vbuf[2][8192];    // 32 KB (Opart at end)
    __shared__ __attribute__((aligned(16))) _Float16 Qrel[64 * QRS];   // 33 KB
    __shared__ float MLm[8][32];
    __shared__ float MLl[8][32];

    const int tid  = threadIdx.x;
    const int wave = tid >> 6;
    const int lane = tid & 63;
    const int dq = lane & 31;      // col index (q for S, d-local for O)
    const int h  = lane >> 5;
    const int qh = wave & 1;       // q half: rows [32qh, 32qh+32)
    const int kq = wave >> 1;      // kv quarter: rows [32kq, 32kq+32) of supertile

    const int wk = ((blockIdx.x & 7) << 6) + (blockIdx.x >> 3);  // XCD-chunked
    const int bh = wk >> 5;
    const int q0 = (wk & 31) * 64;
    const size_t hoff = (size_t)bh * S_LEN * HDIM;

    const char* kimg = (const char*)Kh + (size_t)bh * NT * 8192;
    const char* vimg = (const char*)Vp + (size_t)bh * NT * 8192;

    // ---- prologue: stage V supertile 0 (old-tiles 0,1 -> Vbuf[0]) ----
    load_lds16(vimg + tid * 16,        (char*)&Vbuf[0][0] + tid * 16);
    load_lds16(vimg + 8192 + tid * 16, (char*)&Vbuf[0][0] + 8192 + tid * 16);

    // ---- Q fragments: bq[ki][j] = Q[qb0+dq][16ki+8h+j] * 0.125 ----
    const int qb0 = q0 + 32 * qh;
    half8 bq[4];
#pragma unroll
    for (int ki = 0; ki < 4; ++ki) {
        const float* src = Qg + hoff + (size_t)(qb0 + dq) * HDIM + 16 * ki + 8 * h;
        f32x4 f0 = *(const f32x4*)(src);
        f32x4 f1 = *(const f32x4*)(src + 4);
        half8 hq;
#pragma unroll
        for (int j = 0; j < 4; ++j) {
            hq[j]     = (_Float16)(f0[j] * 0.125f);
            hq[j + 4] = (_Float16)(f1[j] * 0.125f);
        }
        bq[ki] = hq;
    }

    // ---- qrel build: waves 0..3 via 16x16x32 path (rows 16*wave..16*wave+16) ----
    if (wave < 4) {
        const int c = lane & 15, g = lane >> 4;
        half8 aq[2];
#pragma unroll
        for (int kc = 0; kc < 2; ++kc) {
            const float* src = Qg + hoff + (size_t)(q0 + 16 * wave + c) * HDIM + kc * 32 + g * 8;
            f32x4 f0 = *(const f32x4*)(src);
            f32x4 f1 = *(const f32x4*)(src + 4);
            half8 hq;
#pragma unroll
            for (int j = 0; j < 4; ++j) {
                hq[j]     = (_Float16)(f0[j] * 0.125f);
                hq[j + 4] = (_Float16)(f1[j] * 0.125f);
            }
            aq[kc] = hq;
        }
#pragma unroll 1
        for (int t = 0; t < 17; ++t) {
            f32x4 acc = {0.f, 0.f, 0.f, 0.f};
            int r = t * 16 + c;
            if (r > 256) r = 256;
#pragma unroll
            for (int kc = 0; kc < 2; ++kc) {
                const float* src = RELg + (size_t)r * HDIM + kc * 32 + g * 8;
                f32x4 f0 = *(const f32x4*)(src);
                f32x4 f1 = *(const f32x4*)(src + 4);
                half8 b;
#pragma unroll
                for (int j = 0; j < 4; ++j) { b[j] = (_Float16)f0[j]; b[j+4] = (_Float16)f1[j]; }
                acc = __builtin_amdgcn_mfma_f32_16x16x32_f16(aq[kc], b, acc, 0, 0, 0);
            }
            const int col = t * 16 + c;
            if (col <= 256) {
#pragma unroll
                for (int reg = 0; reg < 4; ++reg)
                    Qrel[(16 * wave + 4 * g + reg) * QRS + col] = (_Float16)acc[reg];
            }
        }
    }

    // ---- K fragment invariant offsets + load supertile 0 ----
    const int r64 = 32 * (kq & 1) + dq;          // row within old 64-kv tile
    const int uadd = kq >> 1;                    // which old tile of the pair
    int koff[4];
#pragma unroll
    for (int ki = 0; ki < 4; ++ki)
        koff[ki] = (r64 * 128 + 32 * ki + 16 * h) ^ ((r64 & 7) << 4);

    half8 kA[4], kB[4];
#pragma unroll
    for (int ki = 0; ki < 4; ++ki)
        kA[ki] = *(const half8*)(kimg + (size_t)uadd * 8192 + koff[ki]);

    // ---- V read invariant offsets ----
    const int vhalf = (kq >> 1) * 8192;
    const int gq = kq & 1;
    int voff[2][2];
#pragma unroll
    for (int dh = 0; dh < 2; ++dh)
#pragma unroll
        for (int c = 0; c < 2; ++c) {
            const int d = 32 * dh + dq;
            voff[dh][c] = vhalf + ((d * 128 + gq * 64 + c * 32 + h * 16) ^ ((d & 7) << 4));
        }

    float m = -1e30f, l_run = 0.f;
    f32x16 oacc0 = {0.f}, oacc1 = {0.f};
#pragma unroll
    for (int i = 0; i < 16; ++i) { oacc0[i] = 0.f; oacc1[i] = 0.f; }

    // first body top will vmcnt(0)+barrier (covers V0, kA, Qrel)
    const _Float16* qr = &Qrel[(32 * qh + dq) * QRS];

#define BODY(t, b, KA, KB) do {                                                      \
        asm volatile("s_waitcnt vmcnt(0)" ::: "memory");                             \
        __builtin_amdgcn_s_barrier();                                                \
        {   /* stage V supertile t+1 into Vbuf[b^1] */                               \
            const int tn = ((t) + 1 < NT2) ? (t) + 1 : (t);                          \
            load_lds16(vimg + (size_t)(2 * tn) * 8192 + tid * 16,                    \
                       (char*)&Vbuf[(b) ^ 1][0] + tid * 16);                         \
            load_lds16(vimg + (size_t)(2 * tn + 1) * 8192 + tid * 16,                \
                       (char*)&Vbuf[(b) ^ 1][0] + 8192 + tid * 16);                  \
        }                                                                            \
        f32x16 sacc;                                                                 \
        _Pragma("unroll")                                                            \
        for (int i = 0; i < 16; ++i) sacc[i] = 0.f;                                  \
        __builtin_amdgcn_s_setprio(1);                                               \
        sacc = __builtin_amdgcn_mfma_f32_32x32x16_f16(KA[0], bq[0], sacc, 0, 0, 0);  \
        sacc = __builtin_amdgcn_mfma_f32_32x32x16_f16(KA[1], bq[1], sacc, 0, 0, 0);  \
        sacc = __builtin_amdgcn_mfma_f32_32x32x16_f16(KA[2], bq[2], sacc, 0, 0, 0);  \
        sacc = __builtin_amdgcn_mfma_f32_32x32x16_f16(KA[3], bq[3], sacc, 0, 0, 0);  \
        __builtin_amdgcn_s_setprio(0);                                               \
        {   /* prefetch K frags for supertile t+1 */                                 \
            const int tk = ((t) + 1 < NT2) ? (t) + 1 : (t);                          \
            const char* kb_ = kimg + (size_t)(2 * tk + uadd) * 8192;                 \
            _Pragma("unroll")                                                        \
            for (int ki = 0; ki < 4; ++ki)                                           \
                KB[ki] = *(const half8*)(kb_ + koff[ki]);                            \
        }                                                                            \
        float bias = 0.f, lm;                                                        \
        if (128 * (t) <= q0 - 256) {                                                 \
            bias = (float)qr[0];                                                     \
            lm = sacc[0];                                                            \
            _Pragma("unroll")                                                        \
            for (int i = 1; i < 16; ++i) lm = fmaxf(lm, sacc[i]);                    \
            lm += bias;                                                              \
        } else if (128 * (t) >= q0 + 192) {                                          \
            bias = (float)qr[256];                                                   \
            lm = sacc[0];                                                            \
            _Pragma("unroll")                                                        \
            for (int i = 1; i < 16; ++i) lm = fmaxf(lm, sacc[i]);                    \
            lm += bias;                                                              \
        } else {                                                                     \
            const int base_b = 128 * (t) + 32 * kq + 4 * h - (qb0 + dq) + 128;       \
            lm = -1e30f;                                                             \
            _Pragma("unroll")                                                        \
            for (int r = 0; r < 16; ++r) {                                           \
                int idx = base_b + (r & 3) + 8 * (r >> 2);                           \
                idx = idx < 0 ? 0 : (idx > 256 ? 256 : idx);                         \
                sacc[r] += (float)qr[idx];                                           \
                lm = fmaxf(lm, sacc[r]);                                             \
            }                                                                        \
        }                                                                            \
        lm = fmaxf(lm, __shfl_xor(lm, 32, 64));                                      \
        if (!__all(lm <= m + 8.f)) {                                                 \
            const float mnew = fmaxf(m, lm);                                         \
            const float al = __builtin_amdgcn_exp2f((m - mnew) * L2E);               \
            m = mnew;                                                                \
            l_run *= al;                                                             \
            _Pragma("unroll")                                                        \
            for (int r = 0; r < 16; ++r) {                                           \
                const float ar = __shfl(al, (r & 3) + 8 * (r >> 2) + 4 * h, 64);     \
                oacc0[r] *= ar;                                                      \
                oacc1[r] *= ar;                                                      \
            }                                                                        \
        }                                                                            \
        const float fold = (bias - m) * L2E;                                         \
        float ps = 0.f;                                                              \
        half8 ap0, ap1;                                                              \
        _Pragma("unroll")                                                            \
        for (int j = 0; j < 8; ++j) {                                                \
            const float p0 = __builtin_amdgcn_exp2f(fmaf(sacc[j], L2E, fold));       \
            const float p1 = __builtin_amdgcn_exp2f(fmaf(sacc[8 + j], L2E, fold));   \
            ps += p0 + p1;                                                           \
            ap0[j] = (_Float16)p0;                                                   \
            ap1[j] = (_Float16)p1;                                                   \
        }                                                                            \
        ps += __shfl_xor(ps, 32, 64);                                                \
        l_run += ps;                                                                 \
        const char* vb_ = (const char*)&Vbuf[b][0];                                  \
        half8 v00 = *(const half8*)(vb_ + voff[0][0]);                               \
        half8 v01 = *(const half8*)(vb_ + voff[0][1]);                               \
        half8 v10 = *(const half8*)(vb_ + voff[1][0]);                               \
        half8 v11 = *(const half8*)(vb_ + voff[1][1]);                               \
        __builtin_amdgcn_s_setprio(1);                                               \
        oacc0 = __builtin_amdgcn_mfma_f32_32x32x16_f16(ap0, v00, oacc0, 0, 0, 0);    \
        oacc1 = __builtin_amdgcn_mfma_f32_32x32x16_f16(ap0, v10, oacc1, 0, 0, 0);    \
        oacc0 = __builtin_amdgcn_mfma_f32_32x32x16_f16(ap1, v01, oacc0, 0, 0, 0);    \
        oacc1 = __builtin_amdgcn_mfma_f32_32x32x16_f16(ap1, v11, oacc1, 0, 0, 0);    \
        __builtin_amdgcn_s_setprio(0);                                               \
    } while (0)

#pragma unroll 1
    for (int tt = 0; tt < NT2; tt += 2) {
        BODY(tt,     0, kA, kB);
        BODY(tt + 1, 1, kB, kA);
    }
#undef BODY

    // ---- epilogue: 4-way kq merge in LDS (reuse Vbuf as Opart[q=64][kq=4][d=64]) ----
    asm volatile("s_waitcnt vmcnt(0)" ::: "memory");
    __syncthreads();
    {
        char* Ob = (char*)&Vbuf[0][0];
#pragma unroll
        for (int r = 0; r < 16; ++r) {
            const int q = 32 * qh + (r & 3) + 8 * (r >> 2) + 4 * h;
            _Float16* row = (_Float16*)(Ob + q * 512 + kq * 128);
            row[dq]      = (_Float16)oacc0[r];
            row[32 + dq] = (_Float16)oacc1[r];
        }
        if (lane < 32) {
            MLm[wave][lane] = m;
            MLl[wave][lane] = l_run;
        }
        __syncthreads();

        const int qrow = tid >> 3;           // 0..63
        const int d0   = (tid & 7) * 8;
        const int qh_  = qrow >> 5, qloc = qrow & 31;
        float mm[4], ll[4];
#pragma unroll
        for (int k4 = 0; k4 < 4; ++k4) {
            mm[k4] = MLm[qh_ + 2 * k4][qloc];
            ll[k4] = MLl[qh_ + 2 * k4][qloc];
        }
        const float M = fmaxf(fmaxf(mm[0], mm[1]), fmaxf(mm[2], mm[3]));
        float wgt[4], den = 0.f;
#pragma unroll
        for (int k4 = 0; k4 < 4; ++k4) {
            wgt[k4] = __builtin_amdgcn_exp2f((mm[k4] - M) * L2E);
            den += wgt[k4] * ll[k4];
        }
        const float inv = 1.0f / den;
        float acc[8];
#pragma unroll
        for (int e = 0; e < 8; ++e) acc[e] = 0.f;
        const char* Obr = (const char*)&Vbuf[0][0] + qrow * 512;
#pragma unroll
        for (int k4 = 0; k4 < 4; ++k4) {
            half8 o = *(const half8*)(Obr + k4 * 128 + d0 * 2);
#pragma unroll
            for (int e = 0; e < 8; ++e) acc[e] += (float)o[e] * wgt[k4];
        }
        float* dst = Og + hoff + (size_t)(q0 + qrow) * HDIM + d0;
        f32x4 oA, oB;
#pragma unroll
        for (int j = 0; j < 4; ++j) { oA[j] = acc[j] * inv; oB[j] = acc[4 + j] * inv; }
        *(f32x4*)dst = oA;
        *(f32x4*)(dst + 4) = oB;
    }
}

// ---- fallback (round-1 kernel, used if ws too small) --------------------------------
__global__ __launch_bounds__(256, 2)
void relattn_v1(const float* __restrict__ Qg, const float* __restrict__ Kg,
                const float* __restrict__ Vg, const float* __restrict__ RELg,
                float* __restrict__ Og)
{
    __shared__ _Float16 Klds[64 * HDIM];
    __shared__ _Float16 Vt[HDIM * 64];
    __shared__ _Float16 Plds[4][16 * 64];
    __shared__ _Float16 Qrel[64 * QRS];

    const int tid  = threadIdx.x;
    const int wave = tid >> 6;
    const int lane = tid & 63;
    const int c = lane & 15;
    const int g = lane >> 4;

    const int bid = blockIdx.x;
    const int bh  = bid >> 5;
    const int q0  = (bid & 31) * 64;

    const size_t hoff = (size_t)bh * S_LEN * HDIM;
    const float* Qh = Qg + hoff;
    const float* Kh = Kg + hoff;
    const float* Vh = Vg + hoff;

    const int qrow_frag = q0 + wave * 16 + c;
    half8 aq[2];
#pragma unroll
    for (int kc = 0; kc < 2; ++kc) {
        const float* src = Qh + (size_t)qrow_frag * HDIM + kc * 32 + g * 8;
        f32x4 f0 = *(const f32x4*)(src);
        f32x4 f1 = *(const f32x4*)(src + 4);
        half8 h;
#pragma unroll
        for (int j = 0; j < 4; ++j) {
            h[j]     = (_Float16)(f0[j] * 0.125f);
            h[j + 4] = (_Float16)(f1[j] * 0.125f);
        }
        aq[kc] = h;
    }

#pragma unroll 1
    for (int t = 0; t < 17; ++t) {
        f32x4 acc = {0.f, 0.f, 0.f, 0.f};
        int r = t * 16 + c;
        if (r > 256) r = 256;
#pragma unroll
        for (int kc = 0; kc < 2; ++kc) {
            const float* src = RELg + (size_t)r * HDIM + kc * 32 + g * 8;
            f32x4 f0 = *(const f32x4*)(src);
            f32x4 f1 = *(const f32x4*)(src + 4);
            half8 b;
#pragma unroll
            for (int j = 0; j < 4; ++j) { b[j] = (_Float16)f0[j]; b[j+4] = (_Float16)f1[j]; }
            acc = __builtin_amdgcn_mfma_f32_16x16x32_f16(aq[kc], b, acc, 0, 0, 0);
        }
        const int col = t * 16 + c;
        if (col <= 256) {
#pragma unroll
            for (int reg = 0; reg < 4; ++reg)
                Qrel[(wave * 16 + 4 * g + reg) * QRS + col] = (_Float16)acc[reg];
        }
    }

    float mrow[4], lrow[4];
    f32x4 oacc[4];
#pragma unroll
    for (int i = 0; i < 4; ++i) {
        mrow[i] = -1e30f; lrow[i] = 0.f;
        oacc[i] = (f32x4){0.f, 0.f, 0.f, 0.f};
    }

    for (int k0 = 0; k0 < S_LEN; k0 += 64) {
        __syncthreads();
        {
            const int r  = tid >> 2;
            const int dqv = (tid & 3) << 4;
            const float* src = Kh + (size_t)(k0 + r) * HDIM + dqv;
            f32x4 f0 = *(const f32x4*)(src);
            f32x4 f1 = *(const f32x4*)(src + 4);
            f32x4 f2 = *(const f32x4*)(src + 8);
            f32x4 f3 = *(const f32x4*)(src + 12);
            half8 h0, h1;
#pragma unroll
            for (int j = 0; j < 4; ++j) {
                h0[j] = (_Float16)f0[j]; h0[j+4] = (_Float16)f1[j];
                h1[j] = (_Float16)f2[j]; h1[j+4] = (_Float16)f3[j];
            }
            const int swz = (r & 7) << 4;
            char* base = (char*)Klds;
            *(half8*)(base + ((r * 128 + dqv * 2) ^ swz))      = h0;
            *(half8*)(base + ((r * 128 + dqv * 2 + 16) ^ swz)) = h1;
        }
        {
            const int kv = tid & 63;
            const int dbase = (tid >> 6) << 4;
            const float* src = Vh + (size_t)(k0 + kv) * HDIM + dbase;
            f32x4 f0 = *(const f32x4*)(src);
            f32x4 f1 = *(const f32x4*)(src + 4);
            f32x4 f2 = *(const f32x4*)(src + 8);
            f32x4 f3 = *(const f32x4*)(src + 12);
            float vals[16];
#pragma unroll
            for (int j = 0; j < 4; ++j) {
                vals[j] = f0[j]; vals[4+j] = f1[j]; vals[8+j] = f2[j]; vals[12+j] = f3[j];
            }
            char* base = (char*)Vt;
#pragma unroll
            for (int i = 0; i < 16; ++i) {
                const int d = dbase + i;
                const int off = (d * 128 + kv * 2) ^ ((d & 7) << 4);
                *(_Float16*)(base + off) = (_Float16)vals[i];
            }
        }
        __syncthreads();

        f32x4 sacc[4];
#pragma unroll
        for (int n = 0; n < 4; ++n) sacc[n] = (f32x4){0.f,0.f,0.f,0.f};
#pragma unroll
        for (int kc = 0; kc < 2; ++kc) {
#pragma unroll
            for (int n = 0; n < 4; ++n) {
                const int off = (((16*n + c) * 128) + kc * 64 + g * 16) ^ ((c & 7) << 4);
                half8 bk = *(const half8*)((const char*)Klds + off);
                sacc[n] = __builtin_amdgcn_mfma_f32_16x16x32_f16(aq[kc], bk, sacc[n], 0, 0, 0);
            }
        }

        float sval[4][4];
        const int myq0 = q0 + wave * 16 + 4 * g;
#pragma unroll
        for (int n = 0; n < 4; ++n) {
            const int kpos = k0 + 16 * n + c;
#pragma unroll
            for (int reg = 0; reg < 4; ++reg) {
                int rel = kpos - (myq0 + reg);
                rel = rel < -128 ? -128 : (rel > 128 ? 128 : rel);
                const float bias = (float)Qrel[(wave*16 + 4*g + reg) * QRS + (rel + 128)];
                sval[n][reg] = sacc[n][reg] + bias;
            }
        }

        float mt[4];
#pragma unroll
        for (int reg = 0; reg < 4; ++reg) {
            float mp = fmaxf(fmaxf(sval[0][reg], sval[1][reg]),
                             fmaxf(sval[2][reg], sval[3][reg]));
#pragma unroll
            for (int msk = 1; msk < 16; msk <<= 1)
                mp = fmaxf(mp, __shfl_xor(mp, msk, 64));
            mt[reg] = mp;
        }

        float alpha[4], psum[4];
#pragma unroll
        for (int reg = 0; reg < 4; ++reg) {
            const float mn = fmaxf(mrow[reg], mt[reg]);
            alpha[reg] = __expf(mrow[reg] - mn);
            mrow[reg] = mn;
            psum[reg] = 0.f;
        }

        char* pbase = (char*)&Plds[wave][0];
#pragma unroll
        for (int n = 0; n < 4; ++n) {
#pragma unroll
            for (int reg = 0; reg < 4; ++reg) {
                const float pv = __expf(sval[n][reg] - mrow[reg]);
                psum[reg] += pv;
                const int row = 4 * g + reg;
                const int off = (row * 128 + (16 * n + c) * 2) ^ ((row & 7) << 4);
                *(_Float16*)(pbase + off) = (_Float16)pv;
            }
        }

#pragma unroll
        for (int reg = 0; reg < 4; ++reg) {
            float ps = psum[reg];
#pragma unroll
            for (int msk = 1; msk < 16; msk <<= 1)
                ps += __shfl_xor(ps, msk, 64);
            lrow[reg] = lrow[reg] * alpha[reg] + ps;
#pragma unroll
            for (int dn = 0; dn < 4; ++dn) oacc[dn][reg] *= alpha[reg];
        }

        asm volatile("s_waitcnt lgkmcnt(0)" ::: "memory");

        half8 ap[2];
#pragma unroll
        for (int kc = 0; kc < 2; ++kc) {
            const int off = (c * 128 + kc * 64 + g * 16) ^ ((c & 7) << 4);
            ap[kc] = *(const half8*)(pbase + off);
        }
#pragma unroll
        for (int kc = 0; kc < 2; ++kc) {
#pragma unroll
            for (int dn = 0; dn < 4; ++dn) {
                const int drow = 16 * dn + c;
                const int off = (drow * 128 + kc * 64 + g * 16) ^ ((c & 7) << 4);
                half8 bv = *(const half8*)((const char*)Vt + off);
                oacc[dn] = __builtin_amdgcn_mfma_f32_16x16x32_f16(ap[kc], bv, oacc[dn], 0, 0, 0);
            }
        }
    }

#pragma unroll
    for (int reg = 0; reg < 4; ++reg) {
        const float inv = 1.0f / lrow[reg];
        const int row = q0 + wave * 16 + 4 * g + reg;
        float* dst = Og + hoff + (size_t)row * HDIM + c;
#pragma unroll
        for (int dn = 0; dn < 4; ++dn)
            dst[16 * dn] = oacc[dn][reg] * inv;
    }
}

extern "C" void kernel_launch(void* const* d_in, const int* in_sizes, int n_in,
                              void* d_out, int out_size, void* d_ws, size_t ws_size,
                              hipStream_t stream) {
    const float* q   = (const float*)d_in[0];
    const float* k   = (const float*)d_in[1];
    const float* v   = (const float*)d_in[2];
    const float* rel = (const float*)d_in[3];
    float* out = (float*)d_out;
    (void)in_sizes; (void)n_in; (void)out_size;

    const size_t kv_bytes = (size_t)NBH * S_LEN * HDIM * sizeof(_Float16);  // 4 MB each
    if (ws_size >= 2 * kv_bytes) {
        _Float16* KhB = (_Float16*)d_ws;
        _Float16* VpB = (_Float16*)((char*)d_ws + kv_bytes);
        convert_kv_kernel<<<dim3(1536), 256, 0, stream>>>(k, v, KhB, VpB);
        relattn_v11<<<dim3(512), 512, 0, stream>>>(q, rel, KhB, VpB, out);
    } else {
        relattn_v1<<<dim3(512), 256, 0, stream>>>(q, k, v, rel, out);
    }
}